// Round 5
// baseline (209.578 us; speedup 1.0000x reference)
//
#include <hip/hip_runtime.h>

#define NN 100000
#define NE 1600000
#define DD 64
#define P    1563    // 64-row fine partitions: f = row >> 6
#define NB   196     // 512-row coarse buckets: b = row >> 9
#define NBK1 391     // K1 blocks, 4096 edges each (391*4096 >= NE)
#define NSUB 10      // K2 slices per bucket (10*1024 = BCAP)
#define BCAP 10240   // records per bucket slab (mean 8192, ~23 sigma)
#define PCAP 1536    // records per fine partition slab (mean 1024, ~16 sigma)
#define ECAP 1536    // LDS padded edge buffer in K3

__device__ __forceinline__ unsigned short f2bfu(float f) {
    union { float f; unsigned u; } c; c.f = f;
    unsigned lsb = (c.u >> 16) & 1u;
    c.u += 0x7FFFu + lsb;
    return (unsigned short)(c.u >> 16);
}

typedef short v8s __attribute__((ext_vector_type(8)));
typedef float v4f __attribute__((ext_vector_type(4)));

// ===== K0: init: zero cursors, pre-convert W0/W1 -> bf16 =====
__global__ __launch_bounds__(256) void init_kernel(
    const float* __restrict__ W0, const float* __restrict__ W1,
    int* __restrict__ gbcur, int* __restrict__ fcur,
    unsigned short* __restrict__ wb0, unsigned short* __restrict__ wb1)
{
    int i = blockIdx.x * 256 + threadIdx.x;     // grid 16*256 = 4096 threads
    if (i < NB) gbcur[i] = 0;
    if (i < NB * 8) fcur[i] = 0;
    if (i < DD * DD) { wb0[i] = f2bfu(W0[i]); wb1[i] = f2bfu(W1[i]); }
}

// ===== K1: coarse bucket scatter, 512-thread blocks (8 waves for latency hiding) =====
// Record: (col | row_local9 << 20, val); runs of ~21 records stay coalesced.
__global__ __launch_bounds__(512) void bucket_scatter_kernel(
    const int* __restrict__ row, const int* __restrict__ col,
    const float* __restrict__ val, int* __restrict__ gbcur,
    int2* __restrict__ bslab)
{
    __shared__ int hist[NB];                 // 784 B
    int b = blockIdx.x, t = threadIdx.x;
    if (t < NB) hist[t] = 0;
    __syncthreads();

    int4 r[2], c[2]; float4 v[2]; bool ok[2];
#pragma unroll
    for (int h = 0; h < 2; ++h) {
        int e = b * 4096 + h * 2048 + t * 4;
        ok[h] = (e + 3 < NE);
        if (ok[h]) {
            r[h] = *(const int4*)(row + e);
            c[h] = *(const int4*)(col + e);
            v[h] = *(const float4*)(val + e);
            atomicAdd(&hist[r[h].x >> 9], 1);
            atomicAdd(&hist[r[h].y >> 9], 1);
            atomicAdd(&hist[r[h].z >> 9], 1);
            atomicAdd(&hist[r[h].w >> 9], 1);
        }
    }
    __syncthreads();
    if (t < NB) {
        int cnt = hist[t];
        hist[t] = cnt ? atomicAdd(&gbcur[t], cnt) : 0;
    }
    __syncthreads();
#pragma unroll
    for (int h = 0; h < 2; ++h) {
        if (ok[h]) {
            int b0_ = r[h].x >> 9, b1_ = r[h].y >> 9;
            int b2_ = r[h].z >> 9, b3_ = r[h].w >> 9;
            int q0 = atomicAdd(&hist[b0_], 1);
            int q1 = atomicAdd(&hist[b1_], 1);
            int q2 = atomicAdd(&hist[b2_], 1);
            int q3 = atomicAdd(&hist[b3_], 1);
            if (q0 < BCAP) bslab[(size_t)b0_ * BCAP + q0] =
                make_int2(c[h].x | ((r[h].x & 511) << 20), __float_as_int(v[h].x));
            if (q1 < BCAP) bslab[(size_t)b1_ * BCAP + q1] =
                make_int2(c[h].y | ((r[h].y & 511) << 20), __float_as_int(v[h].y));
            if (q2 < BCAP) bslab[(size_t)b2_ * BCAP + q2] =
                make_int2(c[h].z | ((r[h].z & 511) << 20), __float_as_int(v[h].z));
            if (q3 < BCAP) bslab[(size_t)b3_ * BCAP + q3] =
                make_int2(c[h].w | ((r[h].w & 511) << 20), __float_as_int(v[h].w));
        }
    }
}

// ===== K2: fine scatter, 10 slice-blocks per bucket (1960 blocks, 7.6/CU) =====
// Each slice reserves per-fine-partition ranges via one global atomic per bin;
// within-partition order is permuted (f32 sum order only).
__global__ __launch_bounds__(256) void fine_scatter_kernel(
    const int* __restrict__ gbcur, const int2* __restrict__ bslab,
    int* __restrict__ fcur, int2* __restrict__ fslab)
{
    __shared__ int cur8[8];
    int blk = blockIdx.x;
    int b = blk / NSUB, s = blk - b * NSUB;
    int nb = min(gbcur[b], BCAP);
    int lo = s * 1024, hi = min(nb, lo + 1024);
    if (lo >= hi) return;                    // block-uniform early exit
    int t = threadIdx.x;
    if (t < 8) cur8[t] = 0;
    __syncthreads();

    const int2* bp = bslab + (size_t)b * BCAP;
    int2 recs[4]; int lps[4]; int nr = 0;
#pragma unroll
    for (int k = 0; k < 4; ++k) {
        int idx = lo + k * 256 + t;
        if (idx < hi) {
            recs[nr] = bp[idx];
            lps[nr] = ((recs[nr].x >> 20) & 511) >> 6;
            atomicAdd(&cur8[lps[nr]], 1);
            ++nr;
        }
    }
    __syncthreads();
    if (t < 8) {
        int cnt = cur8[t];
        cur8[t] = cnt ? atomicAdd(&fcur[b * 8 + t], cnt) : 0;
    }
    __syncthreads();
#pragma unroll
    for (int k = 0; k < 4; ++k) {
        if (k < nr) {
            int rl = (recs[k].x >> 20) & 511;
            int pos = atomicAdd(&cur8[lps[k]], 1);
            if (pos < PCAP)
                fslab[(size_t)(b * 8 + lps[k]) * PCAP + pos] =
                    make_int2((recs[k].x & 0x1FFFF) | ((rl & 63) << 20), recs[k].y);
        }
    }
}

// 2-record gather-FMA step (tail path)
#define GR2(ACC, BASE, CH) { \
    int2 r0_ = ebuf[(BASE) + (CH) * 8 + q]; \
    int2 r1_ = ebuf[(BASE) + (CH) * 8 + 4 + q]; \
    float4 f0_ = *(const float4*)(x + (size_t)r0_.x * DD + sub * 4); \
    float4 f1_ = *(const float4*)(x + (size_t)r1_.x * DD + sub * 4); \
    float v0_ = __int_as_float(r0_.y), v1_ = __int_as_float(r1_.y); \
    ACC.x = fmaf(v0_, f0_.x, ACC.x); ACC.y = fmaf(v0_, f0_.y, ACC.y); \
    ACC.z = fmaf(v0_, f0_.z, ACC.z); ACC.w = fmaf(v0_, f0_.w, ACC.w); \
    ACC.x = fmaf(v1_, f1_.x, ACC.x); ACC.y = fmaf(v1_, f1_.y, ACC.y); \
    ACC.z = fmaf(v1_, f1_.z, ACC.z); ACC.w = fmaf(v1_, f1_.w, ACC.w); }

// ===== K3: fused in-LDS sort + pull-SpMM (row-paired, 8 gathers in flight) + MFMA =====
__global__ __launch_bounds__(256, 4) void sort_pull_mfma_kernel(
    const float* __restrict__ x, const int* __restrict__ fcnt,
    const int2* __restrict__ fslab,
    const unsigned short* __restrict__ wb0, const unsigned short* __restrict__ wb1,
    const float* __restrict__ b0, const float* __restrict__ s0, const float* __restrict__ o0,
    const float* __restrict__ b1, const float* __restrict__ s1, const float* __restrict__ o1,
    float* __restrict__ out)
{
    __shared__ int2 ebuf[ECAP];              // 12288 B
    __shared__ unsigned aggt[4][16][36];     // 9216 B (16x64 bf16/wave)
    __shared__ int rcnt[64];
    __shared__ int pscan[64];
    __shared__ int rcur[64];
    __shared__ int pstart[65];               // total ~22.5 KB

    int p = blockIdx.x, t = threadIdx.x;
    int np = min(fcnt[p], PCAP);
    const int2* sp = fslab + (size_t)p * PCAP;

    // ---- phase 1: slab -> registers (single global read), count rows ----
    int2 rec[6]; int nrec = 0;
    if (t < 64) rcnt[t] = 0;
    __syncthreads();
#pragma unroll
    for (int k = 0; k < 6; ++k) {
        int i = t + k * 256;
        if (i < np) {
            rec[k] = sp[i]; ++nrec;
            atomicAdd(&rcnt[(rec[k].x >> 20) & 63], 1);
        }
    }
    __syncthreads();
    // ---- phase 2: 8-padded exclusive scan of row counts ----
    if (t < 64) pscan[t] = (rcnt[t] + 7) & ~7;
    __syncthreads();
    for (int off = 1; off < 64; off <<= 1) {
        int u = 0;
        if (t < 64 && t >= off) u = pscan[t - off];
        __syncthreads();
        if (t < 64) pscan[t] += u;
        __syncthreads();
    }
    if (t < 64) pstart[t + 1] = min(pscan[t], ECAP);
    if (t == 0) pstart[0] = 0;
    __syncthreads();
    if (t < 64) {
        rcur[t] = pstart[t];
        int s = min(pstart[t] + rcnt[t], ECAP);
        int e = pstart[t + 1];
        for (int j = s; j < e; ++j) ebuf[j] = make_int2(0, 0);  // zero pads
    }
    __syncthreads();
#pragma unroll
    for (int k = 0; k < 6; ++k) {
        if (k < nrec) {
            int pos = atomicAdd(&rcur[(rec[k].x >> 20) & 63], 1);
            if (pos < ECAP) ebuf[pos] = make_int2(rec[k].x & 0x1FFFF, rec[k].y);
        }
    }
    __syncthreads();

    // ---- phase 3: row-paired gather-aggregate (8 loads in flight/wave) ----
    int lane = t & 63, wv = t >> 6;
    int sub = lane & 15, q = lane >> 4;
    for (int rp = 0; rp < 8; ++rp) {
        int rA = wv * 16 + rp * 2;
        int sA = pstart[rA];
        int sB = pstart[rA + 1];
        int eB = pstart[rA + 2];
        int ccA = (sB - sA) >> 3;
        int ccB = (eB - sB) >> 3;
        float4 aA = make_float4(0.f, 0.f, 0.f, 0.f);
        float4 aB = make_float4(0.f, 0.f, 0.f, 0.f);
        int cA = 0, cB = 0;
        while (cA + 2 <= ccA && cB + 2 <= ccB) {   // common case: 1 iter (deg<=16)
            int2 ra0 = ebuf[sA + cA * 8 + q];
            int2 ra1 = ebuf[sA + cA * 8 + 4 + q];
            int2 ra2 = ebuf[sA + cA * 8 + 8 + q];
            int2 ra3 = ebuf[sA + cA * 8 + 12 + q];
            int2 rb0 = ebuf[sB + cB * 8 + q];
            int2 rb1 = ebuf[sB + cB * 8 + 4 + q];
            int2 rb2 = ebuf[sB + cB * 8 + 8 + q];
            int2 rb3 = ebuf[sB + cB * 8 + 12 + q];
            float4 fa0 = *(const float4*)(x + (size_t)ra0.x * DD + sub * 4);
            float4 fa1 = *(const float4*)(x + (size_t)ra1.x * DD + sub * 4);
            float4 fa2 = *(const float4*)(x + (size_t)ra2.x * DD + sub * 4);
            float4 fa3 = *(const float4*)(x + (size_t)ra3.x * DD + sub * 4);
            float4 fb0 = *(const float4*)(x + (size_t)rb0.x * DD + sub * 4);
            float4 fb1 = *(const float4*)(x + (size_t)rb1.x * DD + sub * 4);
            float4 fb2 = *(const float4*)(x + (size_t)rb2.x * DD + sub * 4);
            float4 fb3 = *(const float4*)(x + (size_t)rb3.x * DD + sub * 4);
            float va0 = __int_as_float(ra0.y), va1 = __int_as_float(ra1.y);
            float va2 = __int_as_float(ra2.y), va3 = __int_as_float(ra3.y);
            float vb0 = __int_as_float(rb0.y), vb1 = __int_as_float(rb1.y);
            float vb2 = __int_as_float(rb2.y), vb3 = __int_as_float(rb3.y);
            aA.x = fmaf(va0, fa0.x, aA.x); aA.y = fmaf(va0, fa0.y, aA.y);
            aA.z = fmaf(va0, fa0.z, aA.z); aA.w = fmaf(va0, fa0.w, aA.w);
            aA.x = fmaf(va1, fa1.x, aA.x); aA.y = fmaf(va1, fa1.y, aA.y);
            aA.z = fmaf(va1, fa1.z, aA.z); aA.w = fmaf(va1, fa1.w, aA.w);
            aA.x = fmaf(va2, fa2.x, aA.x); aA.y = fmaf(va2, fa2.y, aA.y);
            aA.z = fmaf(va2, fa2.z, aA.z); aA.w = fmaf(va2, fa2.w, aA.w);
            aA.x = fmaf(va3, fa3.x, aA.x); aA.y = fmaf(va3, fa3.y, aA.y);
            aA.z = fmaf(va3, fa3.z, aA.z); aA.w = fmaf(va3, fa3.w, aA.w);
            aB.x = fmaf(vb0, fb0.x, aB.x); aB.y = fmaf(vb0, fb0.y, aB.y);
            aB.z = fmaf(vb0, fb0.z, aB.z); aB.w = fmaf(vb0, fb0.w, aB.w);
            aB.x = fmaf(vb1, fb1.x, aB.x); aB.y = fmaf(vb1, fb1.y, aB.y);
            aB.z = fmaf(vb1, fb1.z, aB.z); aB.w = fmaf(vb1, fb1.w, aB.w);
            aB.x = fmaf(vb2, fb2.x, aB.x); aB.y = fmaf(vb2, fb2.y, aB.y);
            aB.z = fmaf(vb2, fb2.z, aB.z); aB.w = fmaf(vb2, fb2.w, aB.w);
            aB.x = fmaf(vb3, fb3.x, aB.x); aB.y = fmaf(vb3, fb3.y, aB.y);
            aB.z = fmaf(vb3, fb3.z, aB.z); aB.w = fmaf(vb3, fb3.w, aB.w);
            cA += 2; cB += 2;
        }
        for (; cA + 2 <= ccA; cA += 2) { GR2(aA, sA, cA); GR2(aA, sA, cA + 1); }
        if (cA < ccA) GR2(aA, sA, cA);
        for (; cB + 2 <= ccB; cB += 2) { GR2(aB, sB, cB); GR2(aB, sB, cB + 1); }
        if (cB < ccB) GR2(aB, sB, cB);

        aA.x += __shfl_xor(aA.x, 16, 64); aA.y += __shfl_xor(aA.y, 16, 64);
        aA.z += __shfl_xor(aA.z, 16, 64); aA.w += __shfl_xor(aA.w, 16, 64);
        aA.x += __shfl_xor(aA.x, 32, 64); aA.y += __shfl_xor(aA.y, 32, 64);
        aA.z += __shfl_xor(aA.z, 32, 64); aA.w += __shfl_xor(aA.w, 32, 64);
        aB.x += __shfl_xor(aB.x, 16, 64); aB.y += __shfl_xor(aB.y, 16, 64);
        aB.z += __shfl_xor(aB.z, 16, 64); aB.w += __shfl_xor(aB.w, 16, 64);
        aB.x += __shfl_xor(aB.x, 32, 64); aB.y += __shfl_xor(aB.y, 32, 64);
        aB.z += __shfl_xor(aB.z, 32, 64); aB.w += __shfl_xor(aB.w, 32, 64);
        if (q == 0) {
            uint2 pkA, pkB;
            pkA.x = (unsigned)f2bfu(aA.x) | ((unsigned)f2bfu(aA.y) << 16);
            pkA.y = (unsigned)f2bfu(aA.z) | ((unsigned)f2bfu(aA.w) << 16);
            pkB.x = (unsigned)f2bfu(aB.x) | ((unsigned)f2bfu(aB.y) << 16);
            pkB.y = (unsigned)f2bfu(aB.z) | ((unsigned)f2bfu(aB.w) << 16);
            *(uint2*)&aggt[wv][rp * 2][sub * 2] = pkA;
            *(uint2*)&aggt[wv][rp * 2 + 1][sub * 2] = pkB;
        }
    }
    // per-wave tile written by this wave only -> DS pipe is in-order per wave

    // ---- phase 4: two-hop MFMA transform + rownorm for this wave's 16 nodes ----
    int nb0 = p * 64 + wv * 16;
    if (nb0 >= NN) return;                   // tail partitions: whole waves only

    v8s ax[2], aa[2];
#pragma unroll
    for (int ks = 0; ks < 2; ++ks) {
        const float* px = x + (size_t)(nb0 + sub) * DD + ks * 32 + q * 8;
        float4 a0 = *(const float4*)px, a1 = *(const float4*)(px + 4);
        v8s w;
        w[0] = (short)f2bfu(a0.x); w[1] = (short)f2bfu(a0.y);
        w[2] = (short)f2bfu(a0.z); w[3] = (short)f2bfu(a0.w);
        w[4] = (short)f2bfu(a1.x); w[5] = (short)f2bfu(a1.y);
        w[6] = (short)f2bfu(a1.z); w[7] = (short)f2bfu(a1.w);
        ax[ks] = w;
        aa[ks] = *(const v8s*)&aggt[wv][sub][ks * 16 + q * 4];
    }

    float h0v[4][4], h1v[4][4];
    float sr0[4] = {0,0,0,0}, sq0[4] = {0,0,0,0};
    float sr1[4] = {0,0,0,0}, sq1[4] = {0,0,0,0};
#pragma unroll
    for (int dt = 0; dt < 4; ++dt) {
        int nidx = dt * 16 + sub;
        float bi0 = b0[nidx], bi1 = b1[nidx];
        v8s w00 = *(const v8s*)(wb0 + nidx * 64 + q * 8);
        v8s w01 = *(const v8s*)(wb0 + nidx * 64 + 32 + q * 8);
        v8s w10 = *(const v8s*)(wb1 + nidx * 64 + q * 8);
        v8s w11 = *(const v8s*)(wb1 + nidx * 64 + 32 + q * 8);
        v4f c0 = (v4f){bi0, bi0, bi0, bi0};
        v4f c1 = (v4f){bi1, bi1, bi1, bi1};
        c0 = __builtin_amdgcn_mfma_f32_16x16x32_bf16(ax[0], w00, c0, 0, 0, 0);
        c0 = __builtin_amdgcn_mfma_f32_16x16x32_bf16(ax[1], w01, c0, 0, 0, 0);
        c1 = __builtin_amdgcn_mfma_f32_16x16x32_bf16(aa[0], w10, c1, 0, 0, 0);
        c1 = __builtin_amdgcn_mfma_f32_16x16x32_bf16(aa[1], w11, c1, 0, 0, 0);
#pragma unroll
        for (int r = 0; r < 4; ++r) {
            float h = fmaxf(c0[r], 0.f); h0v[dt][r] = h; sr0[r] += h; sq0[r] += h * h;
            float g = fmaxf(c1[r], 0.f); h1v[dt][r] = g; sr1[r] += g; sq1[r] += g * g;
        }
    }
#pragma unroll
    for (int off = 1; off < 16; off <<= 1) {
#pragma unroll
        for (int r = 0; r < 4; ++r) {
            sr0[r] += __shfl_xor(sr0[r], off, 64);
            sq0[r] += __shfl_xor(sq0[r], off, 64);
            sr1[r] += __shfl_xor(sr1[r], off, 64);
            sq1[r] += __shfl_xor(sq1[r], off, 64);
        }
    }

    float scl0[4], scl1[4], ofs0[4], ofs1[4];
#pragma unroll
    for (int dt = 0; dt < 4; ++dt) {
        int nidx = dt * 16 + sub;
        scl0[dt] = s0[nidx]; scl1[dt] = s1[nidx];
        ofs0[dt] = o0[nidx]; ofs1[dt] = o1[nidx];
    }

    const float inv = 1.0f / 64.0f;
#pragma unroll
    for (int r = 0; r < 4; ++r) {
        float m0 = sr0[r] * inv;
        float v0 = fmaxf(sq0[r] * inv - m0 * m0, 0.f) + 1e-9f;
        float m1 = sr1[r] * inv;
        float v1 = fmaxf(sq1[r] * inv - m1 * m1, 0.f) + 1e-9f;
        float rs0 = rsqrtf(v0), rs1 = rsqrtf(v1);
        int node = nb0 + q * 4 + r;
#pragma unroll
        for (int dt = 0; dt < 4; ++dt) {
            float rv = (h0v[dt][r] - m0) * scl0[dt] * rs0 + ofs0[dt]
                     + (h1v[dt][r] - m1) * scl1[dt] * rs1 + ofs1[dt];
            out[(size_t)node * DD + dt * 16 + sub] = rv;
        }
    }
}

extern "C" void kernel_launch(void* const* d_in, const int* in_sizes, int n_in,
                              void* d_out, int out_size, void* d_ws, size_t ws_size,
                              hipStream_t stream) {
    const float* x  = (const float*)d_in[0];
    const float* ev = (const float*)d_in[1];
    const float* W0 = (const float*)d_in[2];
    const float* b0 = (const float*)d_in[3];
    const float* s0 = (const float*)d_in[4];
    const float* o0 = (const float*)d_in[5];
    const float* W1 = (const float*)d_in[6];
    const float* b1 = (const float*)d_in[7];
    const float* s1 = (const float*)d_in[8];
    const float* o1 = (const float*)d_in[9];
    const int* row = (const int*)d_in[10];
    const int* col = (const int*)d_in[11];

    // ws byte layout (64B-aligned):
    //   gbcur: 0        (784 B, pad 1024)
    //   wb0:   1024     (8192 B)
    //   wb1:   9216     (8192 B)
    //   fcur:  17408    (1568*4 = 6272 B, pad 6400)
    //   bslab: 23808    (196*10240*8 = 16,056,320 B)
    //   fslab: 16080128 (1563*1536*8 = 19,206,144 B)  -- total ~35.3 MB
    char* wsb = (char*)d_ws;
    int*  gbcur = (int*)wsb;
    unsigned short* wb0 = (unsigned short*)(wsb + 1024);
    unsigned short* wb1 = (unsigned short*)(wsb + 9216);
    int*  fcur  = (int*)(wsb + 17408);
    int2* bslab = (int2*)(wsb + 23808);
    int2* fslab = (int2*)(wsb + 16080128);

    init_kernel<<<16, 256, 0, stream>>>(W0, W1, gbcur, fcur, wb0, wb1);
    bucket_scatter_kernel<<<NBK1, 512, 0, stream>>>(row, col, ev, gbcur, bslab);
    fine_scatter_kernel<<<NB * NSUB, 256, 0, stream>>>(gbcur, bslab, fcur, fslab);
    sort_pull_mfma_kernel<<<P, 256, 0, stream>>>(
        x, fcur, fslab, wb0, wb1, b0, s0, o0, b1, s1, o1, (float*)d_out);
}